// Round 8
// baseline (460.774 us; speedup 1.0000x reference)
//
#include <hip/hip_runtime.h>

#define BB 1024
#define TT 512
#define KK 64

typedef float f32x4 __attribute__((ext_vector_type(4)));

// beta history: beta_t[j] = max_i(v_{t-1}[i] + T[i][j]) for t=1..511, stored
// PRE-emission and PRE-mask. 1024*511*64*4 B = 134 MB static device BSS.
__device__ float g_bhist[BB * (TT - 1) * KK];

// ---- wave(64)-wide reductions via butterfly shuffles (epilogues only) ----
__device__ __forceinline__ float wmaxf(float x) {
#pragma unroll
  for (int off = 32; off > 0; off >>= 1) x = fmaxf(x, __shfl_xor(x, off, 64));
  return x;
}
__device__ __forceinline__ float wsumf(float x) {
#pragma unroll
  for (int off = 32; off > 0; off >>= 1) x += __shfl_xor(x, off, 64);
  return x;
}
__device__ __forceinline__ int wsumi(int x) {
#pragma unroll
  for (int off = 32; off > 0; off >>= 1) x += __shfl_xor(x, off, 64);
  return x;
}

// Force 8 table quads VGPR-resident (R4 evidence: defeats the
// remat-by-reload heuristic that produced VGPR=52/64 in R1/R3/R5).
#define PIN8(A)                                                              \
  asm volatile("" : "+v"(A[0]), "+v"(A[1]), "+v"(A[2]), "+v"(A[3]),          \
                    "+v"(A[4]), "+v"(A[5]), "+v"(A[6]), "+v"(A[7]))

// One block = one batch element. 128 threads = 2 waves:
//   wave0: forward algorithm (logZ) + gold score -> nll = logZ - gold
//   wave1: max-only viterbi recurrence (beta streamed to HBM) + equality
//          backtrace (ballot/ffs recovers argmax-first-index lazily).
//
// R8 rationale. R6/R7 failed on v_permlane32_swap_b32 inline-asm: with two
// "+v" operands holding identical values the allocator may coalesce them to
// ONE register at some call sites (self-swap -> both outputs = partner) and
// not at others (one output = own value) -- ill-defined contract; abandoned.
// R8 = R5's PASSING arithmetic (half-split reads + shfl_xor(32) combine,
// absmax 0.0) + R4's PIN-proven table residency. This is the clean test of
// the DS-throughput theory: 8 ds_read_b128/step (half of R2's 16) with
// tables in VGPRs (no per-step L1 replay). DS/step/CU ~870 cyc vs R2's 1536.
extern "C" __global__ void __launch_bounds__(128, 2) crf_all_kernel(
    const float* __restrict__ em,      // [B,T,K]
    const int* __restrict__ tags,      // [B,T]
    const int* __restrict__ mask,      // [B,T]
    const float* __restrict__ trans,   // [K,K]
    const float* __restrict__ startt,  // [K]
    const float* __restrict__ endt,    // [K]
    float* __restrict__ out) {         // [B] nll ++ [B,T] path (as float)
  __shared__ float Tp[KK * KK];  // T'[j][i] at [j*64 + (i^j)] (XOR-swizzled)
  __shared__ __align__(16) float pbuf[KK];  // forward exp(alpha-M)
  __shared__ __align__(16) float vbuf[KK];  // viterbi v broadcast

  const int b = blockIdx.x;
  const int lane = threadIdx.x & 63;
  const int is_hi = (lane >> 5) & 1;  // which i-half this lane sums
  const int base = is_hi * 32;        // i in [base, base+32)
  const int jx = lane ^ 32;           // partner column
  const float* emb = em + (size_t)b * TT * KK;
  const int* maskb = mask + b * TT;
  const int* tagsb = tags + b * TT;

  if (threadIdx.x < 64) {
    // ---------------- wave0: forward (logZ) + gold score ----------------
    // Eo[q][u] = exp(T[base+4q+u][lane]), Ex[q][u] = exp(T[base+4q+u][jx]).
    f32x4 Eo[8], Ex[8];
#pragma unroll
    for (int q = 0; q < 8; ++q) {
#pragma unroll
      for (int u = 0; u < 4; ++u) {
        Eo[q][u] = __expf(trans[(base + 4 * q + u) * KK + lane]);
        Ex[q][u] = __expf(trans[(base + 4 * q + u) * KK + jx]);
      }
    }
    PIN8(Eo);
    PIN8(Ex);

    float alpha = startt[lane] + emb[lane];

    auto fwd_step = [&](int t, float emv) {
      int m = maskb[t];  // wave-uniform -> scalar path, off the LDS pipe
      // Stabilization point: ANY in-range M works (harness tol ~49 abs);
      // readfirstlane passed all prior rounds (absmax 0.0).
      float M = __int_as_float(__builtin_amdgcn_readfirstlane(__float_as_int(alpha)));
      float p = __expf(alpha - M);
      pbuf[lane] = p;
      __builtin_amdgcn_wave_barrier();  // same-wave LDS in-order; fence compiler
      float s0 = 0.f, s1 = 0.f, s2 = 0.f, s3 = 0.f;  // own-column partial
      float r0 = 0.f, r1 = 0.f, r2 = 0.f, r3 = 0.f;  // partner-column partial
#pragma unroll
      for (int q = 0; q < 8; ++q) {
        // 2 distinct 16B addresses across the wave; 8 reads/step vs R2's 16:
        // half the CU-shared LDS return traffic.
        float4 pv = *(const float4*)&pbuf[base + q * 4];
        s0 = fmaf(pv.x, Eo[q][0], s0);
        s1 = fmaf(pv.y, Eo[q][1], s1);
        s2 = fmaf(pv.z, Eo[q][2], s2);
        s3 = fmaf(pv.w, Eo[q][3], s3);
        r0 = fmaf(pv.x, Ex[q][0], r0);
        r1 = fmaf(pv.y, Ex[q][1], r1);
        r2 = fmaf(pv.z, Ex[q][2], r2);
        r3 = fmaf(pv.w, Ex[q][3], r3);
      }
      __builtin_amdgcn_wave_barrier();
      float po = (s0 + s1) + (s2 + s3);
      float px = (r0 + r1) + (r2 + r3);
      // lane l^32 computed the other i-half of column l as ITS partner sum.
      // shfl_xor(32): ds_permute path -- PROVEN correct in R5 (absmax 0.0).
      float y = po + __shfl_xor(px, 32, 64);
      float na = __logf(y) + M + emv;
      alpha = (m != 0) ? na : alpha;
    };

    // depth-8 register prefetch ring over t
    float er[8];
#pragma unroll
    for (int k = 0; k < 8; ++k) er[k] = emb[(size_t)(1 + k) * KK + lane];
    for (int tb = 1; tb <= TT - 15; tb += 8) {  // t = 1 .. 504
      PIN8(Eo);
      PIN8(Ex);
#pragma unroll
      for (int k = 0; k < 8; ++k) {
        int t = tb + k;
        float emv = er[k];
        int tp = t + 8;
        tp = (tp < TT) ? tp : (TT - 1);  // clamped (redundant loads harmless)
        er[k] = emb[(size_t)tp * KK + lane];
        fwd_step(t, emv);
      }
    }
    PIN8(Eo);
    PIN8(Ex);
#pragma unroll
    for (int k = 0; k < 7; ++k) {  // t = 505 .. 511, ring slots 0..6
      fwd_step(TT - 7 + k, er[k]);
    }

    // logZ = logsumexp(alpha + end) — exact max (runs once)
    float x = alpha + endt[lane];
    float M2 = wmaxf(x);
    float S = wsumf(__expf(x - M2));
    float logZ = __logf(S) + M2;

    // gold score: lane j covers t = u*64 + j
    float acc = 0.f;
    int msum = 0;
#pragma unroll
    for (int u = 0; u < TT / KK; ++u) {
      int t2 = u * KK + lane;
      int tg = tagsb[t2];
      int m = maskb[t2];
      msum += m;
      float mf = (float)m;
      acc = fmaf(emb[(size_t)t2 * KK + tg], mf, acc);
      if (t2 >= 1) acc = fmaf(trans[tagsb[t2 - 1] * KK + tg], mf, acc);
    }
    acc = wsumf(acc);
    msum = wsumi(msum);
    if (lane == 0) {
      float gold = acc + startt[tagsb[0]] + endt[tagsb[msum - 1]];
      out[b] = logZ - gold;
    }
  } else {
    // ---------------- wave1: max-only viterbi + equality backtrace --------
    // To[q][u] = T[base+4q+u][lane], Tx[q][u] = T[base+4q+u][jx].
    f32x4 To[8], Tx[8];
#pragma unroll
    for (int q = 0; q < 8; ++q) {
#pragma unroll
      for (int u = 0; u < 4; ++u) {
        To[q][u] = trans[(base + 4 * q + u) * KK + lane];
        Tx[q][u] = trans[(base + 4 * q + u) * KK + jx];
      }
    }
    // Populate swizzled T' for the backtrace: Tp[j*64 + (i^j)] = T[i][j].
    // 2-way bank aliasing only -> ~0 conflicts (measured 0 since R3).
#pragma unroll
    for (int i = 0; i < KK; ++i) Tp[lane * KK + (i ^ lane)] = trans[i * KK + lane];
    __builtin_amdgcn_wave_barrier();
    PIN8(To);
    PIN8(Tx);

    float* bh = g_bhist + (size_t)b * (TT - 1) * KK;
    float v = startt[lane] + emb[lane];

    auto vit_step = [&](int t, float emv) {
      int m = maskb[t];  // wave-uniform -> scalar path
      vbuf[lane] = v;
      __builtin_amdgcn_wave_barrier();
      // Max-only over own i-half for BOTH columns; candidate set identical
      // to all prior rounds; max is order-independent -> bh bits unchanged,
      // equality backtrace stays exact.
      float m0 = -3.402823466e38f, m1 = m0, n0 = m0, n1 = m0;
#pragma unroll
      for (int q = 0; q < 8; ++q) {
        float4 pv = *(const float4*)&vbuf[base + q * 4];
        float a0 = pv.x + To[q][0];
        float a1 = pv.y + To[q][1];
        float a2 = pv.z + To[q][2];
        float a3 = pv.w + To[q][3];
        float b0 = pv.x + Tx[q][0];
        float b1 = pv.y + Tx[q][1];
        float b2 = pv.z + Tx[q][2];
        float b3 = pv.w + Tx[q][3];
        m0 = fmaxf(m0, fmaxf(a0, a1));  // fuses to v_max3
        m1 = fmaxf(m1, fmaxf(a2, a3));
        n0 = fmaxf(n0, fmaxf(b0, b1));
        n1 = fmaxf(n1, fmaxf(b2, b3));
      }
      __builtin_amdgcn_wave_barrier();
      float po = fmaxf(m0, m1);
      float px = fmaxf(n0, n1);
      // shfl_xor(32) combine -- PROVEN correct in R5 (absmax 0.0).
      float best = fmaxf(po, __shfl_xor(px, 32, 64));
      bh[(size_t)(t - 1) * KK + lane] = best;  // coalesced 256B/step stream-out
      v = (m != 0) ? (best + emv) : v;
    };

    // depth-8 register prefetch ring over t
    float er[8];
#pragma unroll
    for (int k = 0; k < 8; ++k) er[k] = emb[(size_t)(1 + k) * KK + lane];
    for (int tb = 1; tb <= TT - 15; tb += 8) {  // t = 1 .. 504
      PIN8(To);
      PIN8(Tx);
#pragma unroll
      for (int k = 0; k < 8; ++k) {
        int t = tb + k;
        float emv = er[k];
        int tp = t + 8;
        tp = (tp < TT) ? tp : (TT - 1);
        er[k] = emb[(size_t)tp * KK + lane];
        vit_step(t, emv);
      }
    }
    PIN8(To);
    PIN8(Tx);
#pragma unroll
    for (int k = 0; k < 7; ++k) {  // t = 505 .. 511
      vit_step(TT - 7 + k, er[k]);
    }

    // last = argmax(v + end), first-index on exact ties (runs once)
    float sc = v + endt[lane];
    int idx = lane;
#pragma unroll
    for (int off = 32; off > 0; off >>= 1) {
      float osc = __shfl_xor(sc, off, 64);
      int oidx = __shfl_xor(idx, off, 64);
      if (osc > sc || (osc == sc && oidx < idx)) { sc = osc; idx = oidx; }
    }
    // ---- equality backtrace ----
    // Step tt (tag known): scalar beta_tt[tag] = bh[tt-1][tag] via shfl;
    // vector v_{tt-1}[i] = bh[tt-2][i] + em[tt-1][i] (bitwise == forward's v,
    // same operands & add order). score[i] = v[i] + T'[tag][i]; first lane
    // with score==beta is np.argmax. History rows are tag-independent ->
    // chunk-prefetch 8 steps.
    int tag = idx;
    float* pout = out + BB + (size_t)b * TT;
    int tt = TT - 1;
    while (tt >= 9) {  // process tt .. tt-7
      float Brow[9], Erow[8];
      int Mrow[8];
#pragma unroll
      for (int k = 0; k < 9; ++k) Brow[k] = bh[(size_t)(tt - 1 - k) * KK + lane];
#pragma unroll
      for (int k = 0; k < 8; ++k) Erow[k] = emb[(size_t)(tt - 1 - k) * KK + lane];
#pragma unroll
      for (int k = 0; k < 8; ++k) Mrow[k] = maskb[tt - k];
#pragma unroll
      for (int k = 0; k < 8; ++k) {
        if (lane == 0) pout[tt - k] = (float)tag;
        float beta = __shfl(Brow[k], tag, 64);
        float sc2 = (Brow[k + 1] + Erow[k]) + Tp[tag * KK + (lane ^ tag)];
        unsigned long long mm = __ballot(sc2 == beta);
        int nt = (int)__ffsll(mm) - 1;
        tag = (Mrow[k] != 0) ? nt : tag;
      }
      tt -= 8;
    }
    for (; tt >= 2; --tt) {
      if (lane == 0) pout[tt] = (float)tag;
      float beta = __shfl(bh[(size_t)(tt - 1) * KK + lane], tag, 64);
      float sc2 = (bh[(size_t)(tt - 2) * KK + lane] + emb[(size_t)(tt - 1) * KK + lane]) +
                  Tp[tag * KK + (lane ^ tag)];
      unsigned long long mm = __ballot(sc2 == beta);
      int nt = (int)__ffsll(mm) - 1;
      tag = (maskb[tt] != 0) ? nt : tag;
    }
    {  // tt == 1: vector row is v_0 = start + em[0] (bitwise == forward init)
      if (lane == 0) pout[1] = (float)tag;
      float beta = __shfl(bh[lane], tag, 64);
      float sc2 = (startt[lane] + emb[lane]) + Tp[tag * KK + (lane ^ tag)];
      unsigned long long mm = __ballot(sc2 == beta);
      int nt = (int)__ffsll(mm) - 1;
      tag = (maskb[1] != 0) ? nt : tag;
      if (lane == 0) pout[0] = (float)tag;
    }
  }
}

extern "C" void kernel_launch(void* const* d_in, const int* in_sizes, int n_in,
                              void* d_out, int out_size, void* d_ws, size_t ws_size,
                              hipStream_t stream) {
  (void)in_sizes; (void)n_in; (void)out_size; (void)d_ws; (void)ws_size;
  const float* em = (const float*)d_in[0];
  const int* tags = (const int*)d_in[1];
  const int* mask = (const int*)d_in[2];
  const float* trans = (const float*)d_in[3];
  const float* startt = (const float*)d_in[4];
  const float* endt = (const float*)d_in[5];
  float* out = (float*)d_out;
  crf_all_kernel<<<dim3(BB), dim3(128), 0, stream>>>(em, tags, mask, trans,
                                                     startt, endt, out);
}

// Round 9
// 451.350 us; speedup vs baseline: 1.0209x; 1.0209x over previous
//
#include <hip/hip_runtime.h>

#define BB 1024
#define TT 512
#define KK 64

// beta history: beta_t[j] = max_i(v_{t-1}[i] + T[i][j]) for t=1..511, stored
// PRE-emission and PRE-mask. 1024*511*64*4 B = 134 MB static device BSS.
__device__ float g_bhist[BB * (TT - 1) * KK];

// ---- wave(64)-wide reductions via butterfly shuffles (epilogues only) ----
__device__ __forceinline__ float wmaxf(float x) {
#pragma unroll
  for (int off = 32; off > 0; off >>= 1) x = fmaxf(x, __shfl_xor(x, off, 64));
  return x;
}
__device__ __forceinline__ float wsumf(float x) {
#pragma unroll
  for (int off = 32; off > 0; off >>= 1) x += __shfl_xor(x, off, 64);
  return x;
}
__device__ __forceinline__ int wsumi(int x) {
#pragma unroll
  for (int off = 32; off > 0; off >>= 1) x += __shfl_xor(x, off, 64);
  return x;
}

// One-time opacity pin: marks the value as produced by opaque asm, so the
// allocator cannot REMATERIALIZE it by re-running the load/expf chain each
// step (the R1/R3/R5/R8 failure: VGPR collapse + ~160 extra VALU/step of
// reload+addressing). Applied ONCE at init -- unlike R8's repeated pins,
// which forced register copies every 8 steps and regressed.
__device__ __forceinline__ void opaque1(float& x) {
  asm volatile("" : "+v"(x));
}

// One block = one batch element. 128 threads = 2 waves:
//   wave0: forward algorithm (logZ) + gold score -> nll = logZ - gold
//   wave1: max-only viterbi recurrence (beta streamed to HBM) + equality
//          backtrace (ballot/ffs recovers argmax-first-index lazily).
//
// R9 rationale. Evidence: VALUBusy ~64% at 1522+ cyc/step implies ~240 VALU
// instr/wave/step vs ~80 in source -- table remat inflation in every round
// except R2 (VGPR 88), whose per-wave table was a SINGLE 64-entry plain
// array. R5/R8 split the table into two 32-arrays -> VGPR 64 both times.
// R9 = R5's half-split LDS reads (8 ds_read_b128/step, LDS-return floor
// ~123 us chip-wide) + single-array table shape + one-time opacity pins.
// Arithmetic bitwise == R5/R8 (absmax 0.0): same candidate sets, same fp
// pairing/order, shfl_xor(32) combine proven in R5.
extern "C" __global__ void __launch_bounds__(128, 2) crf_all_kernel(
    const float* __restrict__ em,      // [B,T,K]
    const int* __restrict__ tags,      // [B,T]
    const int* __restrict__ mask,      // [B,T]
    const float* __restrict__ trans,   // [K,K]
    const float* __restrict__ startt,  // [K]
    const float* __restrict__ endt,    // [K]
    float* __restrict__ out) {         // [B] nll ++ [B,T] path (as float)
  __shared__ float Tp[KK * KK];  // T'[j][i] at [j*64 + (i^j)] (XOR-swizzled)
  __shared__ int msk[TT];        // mask row, 2 KB (R2 pattern: LDS broadcast)
  __shared__ __align__(16) float pbuf[KK];  // forward exp(alpha-M)
  __shared__ __align__(16) float vbuf[KK];  // viterbi v broadcast

  const int b = blockIdx.x;
  const int lane = threadIdx.x & 63;
  const int base = (lane >> 5) * 32;  // own i-half: [base, base+32)
  const int jx = lane ^ 32;           // partner column
  const float* emb = em + (size_t)b * TT * KK;
  const int* maskb = mask + b * TT;
  const int* tagsb = tags + b * TT;

  // Stage mask row into LDS (R2's best-round pattern). Both waves write
  // identical values (benign race, aligned dwords).
#pragma unroll
  for (int u = 0; u < TT / KK; ++u) msk[u * KK + lane] = maskb[u * KK + lane];
  __builtin_amdgcn_wave_barrier();

  if (threadIdx.x < 64) {
    // ---------------- wave0: forward (logZ) + gold score ----------------
    // Etab[k]    = exp(T[base+k][lane])   (own column,     k=0..31)
    // Etab[32+k] = exp(T[base+k][lane^32]) (partner column, k=0..31)
    // SINGLE 64-entry array == R2's resident shape.
    float Etab[KK];
#pragma unroll
    for (int k = 0; k < 32; ++k) {
      Etab[k] = __expf(trans[(base + k) * KK + lane]);
      Etab[32 + k] = __expf(trans[(base + k) * KK + jx]);
    }
#pragma unroll
    for (int k = 0; k < KK; ++k) opaque1(Etab[k]);  // one-time: forbid remat

    float alpha = startt[lane] + emb[lane];

    auto fwd_step = [&](int t, float emv) {
      int m = msk[t];  // same-address ds_read broadcast (cheap)
      // Stabilization point: ANY in-range M works (harness tol ~49 abs);
      // readfirstlane passed all prior rounds (absmax 0.0).
      float M = __int_as_float(__builtin_amdgcn_readfirstlane(__float_as_int(alpha)));
      float p = __expf(alpha - M);
      pbuf[lane] = p;
      __builtin_amdgcn_wave_barrier();  // same-wave LDS in-order; fence compiler
      float s0 = 0.f, s1 = 0.f, s2 = 0.f, s3 = 0.f;  // own-column partial
      float r0 = 0.f, r1 = 0.f, r2 = 0.f, r3 = 0.f;  // partner-column partial
#pragma unroll
      for (int q = 0; q < 8; ++q) {
        // 2 distinct 16B addresses across the wave; 8 reads/step vs 16:
        // half the CU-shared LDS return traffic (the measured R2 wall).
        float4 pv = *(const float4*)&pbuf[base + q * 4];
        s0 = fmaf(pv.x, Etab[4 * q + 0], s0);
        s1 = fmaf(pv.y, Etab[4 * q + 1], s1);
        s2 = fmaf(pv.z, Etab[4 * q + 2], s2);
        s3 = fmaf(pv.w, Etab[4 * q + 3], s3);
        r0 = fmaf(pv.x, Etab[32 + 4 * q + 0], r0);
        r1 = fmaf(pv.y, Etab[32 + 4 * q + 1], r1);
        r2 = fmaf(pv.z, Etab[32 + 4 * q + 2], r2);
        r3 = fmaf(pv.w, Etab[32 + 4 * q + 3], r3);
      }
      __builtin_amdgcn_wave_barrier();
      float po = (s0 + s1) + (s2 + s3);
      float px = (r0 + r1) + (r2 + r3);
      // lane l^32 computed the other i-half of column l as ITS partner sum.
      // shfl_xor(32) combine: PROVEN correct in R5/R8 (absmax 0.0).
      float y = po + __shfl_xor(px, 32, 64);
      float na = __logf(y) + M + emv;
      alpha = (m != 0) ? na : alpha;
    };

    // depth-8 register prefetch ring over t
    float er[8];
#pragma unroll
    for (int k = 0; k < 8; ++k) er[k] = emb[(size_t)(1 + k) * KK + lane];
    for (int tb = 1; tb <= TT - 15; tb += 8) {  // t = 1 .. 504
#pragma unroll
      for (int k = 0; k < 8; ++k) {
        int t = tb + k;
        float emv = er[k];
        int tp = t + 8;
        tp = (tp < TT) ? tp : (TT - 1);  // clamped (redundant loads harmless)
        er[k] = emb[(size_t)tp * KK + lane];
        fwd_step(t, emv);
      }
    }
#pragma unroll
    for (int k = 0; k < 7; ++k) {  // t = 505 .. 511, ring slots 0..6
      fwd_step(TT - 7 + k, er[k]);
    }

    // logZ = logsumexp(alpha + end) — exact max (runs once)
    float x = alpha + endt[lane];
    float M2 = wmaxf(x);
    float S = wsumf(__expf(x - M2));
    float logZ = __logf(S) + M2;

    // gold score: lane j covers t = u*64 + j
    float acc = 0.f;
    int msum = 0;
#pragma unroll
    for (int u = 0; u < TT / KK; ++u) {
      int t2 = u * KK + lane;
      int tg = tagsb[t2];
      int m = msk[t2];
      msum += m;
      float mf = (float)m;
      acc = fmaf(emb[(size_t)t2 * KK + tg], mf, acc);
      if (t2 >= 1) acc = fmaf(trans[tagsb[t2 - 1] * KK + tg], mf, acc);
    }
    acc = wsumf(acc);
    msum = wsumi(msum);
    if (lane == 0) {
      float gold = acc + startt[tagsb[0]] + endt[tagsb[msum - 1]];
      out[b] = logZ - gold;
    }
  } else {
    // ---------------- wave1: max-only viterbi + equality backtrace --------
    // Ttab[k] = T[base+k][lane]; Ttab[32+k] = T[base+k][lane^32].
    float Ttab[KK];
#pragma unroll
    for (int k = 0; k < 32; ++k) {
      Ttab[k] = trans[(base + k) * KK + lane];
      Ttab[32 + k] = trans[(base + k) * KK + jx];
    }
#pragma unroll
    for (int k = 0; k < KK; ++k) opaque1(Ttab[k]);  // one-time: forbid remat

    // Populate swizzled T' for the backtrace: Tp[j*64 + (i^j)] = T[i][j].
    // 2-way bank aliasing only -> ~0 conflicts (measured 0 since R3).
#pragma unroll
    for (int i = 0; i < KK; ++i) Tp[lane * KK + (i ^ lane)] = trans[i * KK + lane];
    __builtin_amdgcn_wave_barrier();

    float* bh = g_bhist + (size_t)b * (TT - 1) * KK;
    float v = startt[lane] + emb[lane];

    auto vit_step = [&](int t, float emv) {
      int m = msk[t];  // same-address ds_read broadcast
      vbuf[lane] = v;
      __builtin_amdgcn_wave_barrier();
      // Max-only over own i-half for BOTH columns; candidate set identical
      // to all prior rounds; max is order-independent -> bh bits unchanged,
      // equality backtrace stays exact.
      float m0 = -3.402823466e38f, m1 = m0, n0 = m0, n1 = m0;
#pragma unroll
      for (int q = 0; q < 8; ++q) {
        float4 pv = *(const float4*)&vbuf[base + q * 4];
        float a0 = pv.x + Ttab[4 * q + 0];
        float a1 = pv.y + Ttab[4 * q + 1];
        float a2 = pv.z + Ttab[4 * q + 2];
        float a3 = pv.w + Ttab[4 * q + 3];
        float b0 = pv.x + Ttab[32 + 4 * q + 0];
        float b1 = pv.y + Ttab[32 + 4 * q + 1];
        float b2 = pv.z + Ttab[32 + 4 * q + 2];
        float b3 = pv.w + Ttab[32 + 4 * q + 3];
        m0 = fmaxf(m0, fmaxf(a0, a1));  // fuses to v_max3
        m1 = fmaxf(m1, fmaxf(a2, a3));
        n0 = fmaxf(n0, fmaxf(b0, b1));
        n1 = fmaxf(n1, fmaxf(b2, b3));
      }
      __builtin_amdgcn_wave_barrier();
      float po = fmaxf(m0, m1);
      float px = fmaxf(n0, n1);
      // shfl_xor(32) combine -- PROVEN correct in R5/R8 (absmax 0.0).
      float best = fmaxf(po, __shfl_xor(px, 32, 64));
      bh[(size_t)(t - 1) * KK + lane] = best;  // coalesced 256B/step stream-out
      v = (m != 0) ? (best + emv) : v;
    };

    // depth-8 register prefetch ring over t
    float er[8];
#pragma unroll
    for (int k = 0; k < 8; ++k) er[k] = emb[(size_t)(1 + k) * KK + lane];
    for (int tb = 1; tb <= TT - 15; tb += 8) {  // t = 1 .. 504
#pragma unroll
      for (int k = 0; k < 8; ++k) {
        int t = tb + k;
        float emv = er[k];
        int tp = t + 8;
        tp = (tp < TT) ? tp : (TT - 1);
        er[k] = emb[(size_t)tp * KK + lane];
        vit_step(t, emv);
      }
    }
#pragma unroll
    for (int k = 0; k < 7; ++k) {  // t = 505 .. 511
      vit_step(TT - 7 + k, er[k]);
    }

    // last = argmax(v + end), first-index on exact ties (runs once)
    float sc = v + endt[lane];
    int idx = lane;
#pragma unroll
    for (int off = 32; off > 0; off >>= 1) {
      float osc = __shfl_xor(sc, off, 64);
      int oidx = __shfl_xor(idx, off, 64);
      if (osc > sc || (osc == sc && oidx < idx)) { sc = osc; idx = oidx; }
    }
    // ---- equality backtrace ----
    // Step tt (tag known): scalar beta_tt[tag] = bh[tt-1][tag] via shfl;
    // vector v_{tt-1}[i] = bh[tt-2][i] + em[tt-1][i] (bitwise == forward's v,
    // same operands & add order). score[i] = v[i] + T'[tag][i]; first lane
    // with score==beta is np.argmax. History rows are tag-independent ->
    // chunk-prefetch 8 steps.
    int tag = idx;
    float* pout = out + BB + (size_t)b * TT;
    int tt = TT - 1;
    while (tt >= 9) {  // process tt .. tt-7
      float Brow[9], Erow[8];
      int Mrow[8];
#pragma unroll
      for (int k = 0; k < 9; ++k) Brow[k] = bh[(size_t)(tt - 1 - k) * KK + lane];
#pragma unroll
      for (int k = 0; k < 8; ++k) Erow[k] = emb[(size_t)(tt - 1 - k) * KK + lane];
#pragma unroll
      for (int k = 0; k < 8; ++k) Mrow[k] = msk[tt - k];
#pragma unroll
      for (int k = 0; k < 8; ++k) {
        if (lane == 0) pout[tt - k] = (float)tag;
        float beta = __shfl(Brow[k], tag, 64);
        float sc2 = (Brow[k + 1] + Erow[k]) + Tp[tag * KK + (lane ^ tag)];
        unsigned long long mm = __ballot(sc2 == beta);
        int nt = (int)__ffsll(mm) - 1;
        tag = (Mrow[k] != 0) ? nt : tag;
      }
      tt -= 8;
    }
    for (; tt >= 2; --tt) {
      if (lane == 0) pout[tt] = (float)tag;
      float beta = __shfl(bh[(size_t)(tt - 1) * KK + lane], tag, 64);
      float sc2 = (bh[(size_t)(tt - 2) * KK + lane] + emb[(size_t)(tt - 1) * KK + lane]) +
                  Tp[tag * KK + (lane ^ tag)];
      unsigned long long mm = __ballot(sc2 == beta);
      int nt = (int)__ffsll(mm) - 1;
      tag = (msk[tt] != 0) ? nt : tag;
    }
    {  // tt == 1: vector row is v_0 = start + em[0] (bitwise == forward init)
      if (lane == 0) pout[1] = (float)tag;
      float beta = __shfl(bh[lane], tag, 64);
      float sc2 = (startt[lane] + emb[lane]) + Tp[tag * KK + (lane ^ tag)];
      unsigned long long mm = __ballot(sc2 == beta);
      int nt = (int)__ffsll(mm) - 1;
      tag = (msk[1] != 0) ? nt : tag;
      if (lane == 0) pout[0] = (float)tag;
    }
  }
}

extern "C" void kernel_launch(void* const* d_in, const int* in_sizes, int n_in,
                              void* d_out, int out_size, void* d_ws, size_t ws_size,
                              hipStream_t stream) {
  (void)in_sizes; (void)n_in; (void)out_size; (void)d_ws; (void)ws_size;
  const float* em = (const float*)d_in[0];
  const int* tags = (const int*)d_in[1];
  const int* mask = (const int*)d_in[2];
  const float* trans = (const float*)d_in[3];
  const float* startt = (const float*)d_in[4];
  const float* endt = (const float*)d_in[5];
  float* out = (float*)d_out;
  crf_all_kernel<<<dim3(BB), dim3(128), 0, stream>>>(em, tags, mask, trans,
                                                     startt, endt, out);
}